// Round 1
// baseline (2881.595 us; speedup 1.0000x reference)
//
#include <hip/hip_runtime.h>
#include <hip/hip_bf16.h>

#define HID 128

// ---------------- utility kernels ----------------

__global__ void zero_i32(int* __restrict__ p, int n) {
    int i = blockIdx.x * blockDim.x + threadIdx.x;
    if (i < n) p[i] = 0;
}

__global__ void count_deg(const int* __restrict__ dst, int* __restrict__ deg, int E) {
    int e = blockIdx.x * blockDim.x + threadIdx.x;
    if (e < E) atomicAdd(&deg[dst[e]], 1);
}

// single-block exclusive scan over deg[0..n) -> row_ptr[0..n], pos copy
__global__ __launch_bounds__(1024) void scan_deg(const int* __restrict__ deg,
                                                 int* __restrict__ row_ptr,
                                                 int* __restrict__ pos, int n) {
    __shared__ int sums[1024];
    int t = threadIdx.x;
    int chunk = (n + 1023) / 1024;
    int lo = t * chunk, hi = min(lo + chunk, n);
    int s = 0;
    for (int i = lo; i < hi; i++) s += deg[i];
    sums[t] = s;
    __syncthreads();
    for (int off = 1; off < 1024; off <<= 1) {
        int v = (t >= off) ? sums[t - off] : 0;
        __syncthreads();
        sums[t] += v;
        __syncthreads();
    }
    int excl = (t == 0) ? 0 : sums[t - 1];
    for (int i = lo; i < hi; i++) { row_ptr[i] = excl; pos[i] = excl; excl += deg[i]; }
    if (t == 0) row_ptr[n] = sums[1023];
}

__global__ void fill_csr(const int* __restrict__ src, const int* __restrict__ dst,
                         int* __restrict__ pos, int* __restrict__ csr_src, int E) {
    int e = blockIdx.x * blockDim.x + threadIdx.x;
    if (e < E) {
        int p = atomicAdd(&pos[dst[e]], 1);
        csr_src[p] = src[e];
    }
}

// gstart[g] = lower_bound(batch, g), g in [0, G]; batch is sorted
__global__ void graph_starts(const int* __restrict__ batch, int* __restrict__ gstart,
                             int n, int G) {
    int g = blockIdx.x * blockDim.x + threadIdx.x;
    if (g > G) return;
    int lo = 0, hi = n;
    while (lo < hi) { int m = (lo + hi) >> 1; if (batch[m] < g) lo = m + 1; else hi = m; }
    gstart[g] = lo;
}

// z[n] = h[n] + sum_{e in in-edges(n)} h[src(e)]
__global__ __launch_bounds__(256) void agg_kernel(const float* __restrict__ h,
                                                  const int* __restrict__ row_ptr,
                                                  const int* __restrict__ csr_src,
                                                  float* __restrict__ z, int N) {
    int node = blockIdx.x * 2 + (threadIdx.x >> 7);
    int c = threadIdx.x & 127;
    if (node >= N) return;
    float s = h[(size_t)node * HID + c];
    int e0 = row_ptr[node], e1 = row_ptr[node + 1];
    for (int e = e0; e < e1; e++) {
        s += h[(size_t)csr_src[e] * HID + c];
    }
    z[(size_t)node * HID + c] = s;
}

// out[r][c] = act( sum_k in[r][k]*W[k][c] + bias[c] [+ res[r][c]] )
// optional pre-activation copy to pre_out (used for xres update)
template <bool RELU, bool ADD_RES, bool WRITE_PRE>
__global__ __launch_bounds__(256) void linear128(const float* __restrict__ in,
                                                 const float* __restrict__ W,
                                                 const float* __restrict__ bias,
                                                 const float* __restrict__ res,
                                                 float* __restrict__ out,
                                                 float* __restrict__ pre_out, int M) {
    __shared__ float Wl[HID * HID];
    __shared__ float zl[8][HID];
    int t = threadIdx.x;
    {
        const float4* W4 = (const float4*)W;
        float4* Wl4 = (float4*)Wl;
        for (int i = t; i < HID * HID / 4; i += 256) Wl4[i] = W4[i];
    }
    int c = t & 127, half = t >> 7;
    float bc = bias[c];
    int row0 = blockIdx.x * 16;
    for (int sgo = 0; sgo < 16; sgo += 8) {
        int rbase = row0 + sgo;
        __syncthreads();   // protects Wl on first iter, zl reuse after
        {
            int srow = t >> 5;
            int scol = (t & 31) * 4;
            if (rbase + srow < M)
                *(float4*)&zl[srow][scol] =
                    *(const float4*)&in[(size_t)(rbase + srow) * HID + scol];
        }
        __syncthreads();
        int r0 = half * 4;
        float acc0 = 0.f, acc1 = 0.f, acc2 = 0.f, acc3 = 0.f;
#pragma unroll 8
        for (int k4 = 0; k4 < HID / 4; k4++) {
            float4 a0 = *(const float4*)&zl[r0 + 0][k4 * 4];
            float4 a1 = *(const float4*)&zl[r0 + 1][k4 * 4];
            float4 a2 = *(const float4*)&zl[r0 + 2][k4 * 4];
            float4 a3 = *(const float4*)&zl[r0 + 3][k4 * 4];
            float w0 = Wl[(k4 * 4 + 0) * HID + c];
            float w1 = Wl[(k4 * 4 + 1) * HID + c];
            float w2 = Wl[(k4 * 4 + 2) * HID + c];
            float w3 = Wl[(k4 * 4 + 3) * HID + c];
            acc0 += a0.x * w0 + a0.y * w1 + a0.z * w2 + a0.w * w3;
            acc1 += a1.x * w0 + a1.y * w1 + a1.z * w2 + a1.w * w3;
            acc2 += a2.x * w0 + a2.y * w1 + a2.z * w2 + a2.w * w3;
            acc3 += a3.x * w0 + a3.y * w1 + a3.z * w2 + a3.w * w3;
        }
        float accs[4] = {acc0, acc1, acc2, acc3};
#pragma unroll
        for (int j = 0; j < 4; j++) {
            int r = rbase + r0 + j;
            if (r < M) {
                float v = accs[j] + bc;
                if (ADD_RES) v += res[(size_t)r * HID + c];
                if (WRITE_PRE) pre_out[(size_t)r * HID + c] = v;
                out[(size_t)r * HID + c] = RELU ? fmaxf(v, 0.f) : v;
            }
        }
    }
}

// pooled[g][off + c] = sum over nodes of graph g of h[n][c]   (deterministic)
__global__ __launch_bounds__(128) void pool_kernel(const float* __restrict__ h,
                                                   const int* __restrict__ gstart,
                                                   float* __restrict__ pooled,
                                                   int off, int EMB) {
    int g = blockIdx.x, c = threadIdx.x;
    float s = 0.f;
    int n0 = gstart[g], n1 = gstart[g + 1];
    for (int n = n0; n < n1; ++n) s += h[(size_t)n * HID + c];
    pooled[(size_t)g * EMB + off + c] = s;
}

// out[g] = relu(pooled[g] @ w1 + b1) @ w2 + b2
__global__ __launch_bounds__(128) void post_kernel(const float* __restrict__ pooled,
                                                   const float* __restrict__ w1,
                                                   const float* __restrict__ b1,
                                                   const float* __restrict__ w2,
                                                   const float* __restrict__ b2,
                                                   float* __restrict__ out, int EMB) {
    int g = blockIdx.x, c = threadIdx.x;
    extern __shared__ float smem[];           // EMB + HID floats
    float* prow = smem;
    float* y1 = smem + EMB;
    for (int k = c; k < EMB; k += 128) prow[k] = pooled[(size_t)g * EMB + k];
    __syncthreads();
    float acc = b1[c];
    for (int k = 0; k < EMB; k++) acc += prow[k] * w1[k * HID + c];
    y1[c] = fmaxf(acc, 0.f);
    __syncthreads();
    float acc2 = b2[c];
    for (int k = 0; k < HID; k++) acc2 += y1[k] * w2[k * HID + c];
    out[(size_t)g * HID + c] = acc2;
}

// ---------------- launch ----------------

extern "C" void kernel_launch(void* const* d_in, const int* in_sizes, int n_in,
                              void* d_out, int out_size, void* d_ws, size_t ws_size,
                              hipStream_t stream) {
    const float* x       = (const float*)d_in[0];
    const int* edge_index= (const int*)d_in[1];
    const int* batch     = (const int*)d_in[2];
    const float* pre_w   = (const float*)d_in[3];
    const float* pre_b   = (const float*)d_in[4];
    const float* conv_w1 = (const float*)d_in[5];
    const float* conv_b1 = (const float*)d_in[6];
    const float* conv_w2 = (const float*)d_in[7];
    const float* conv_b2 = (const float*)d_in[8];
    const float* post_w1 = (const float*)d_in[9];
    const float* post_b1 = (const float*)d_in[10];
    const float* post_w2 = (const float*)d_in[11];
    const float* post_b2 = (const float*)d_in[12];
    float* outp = (float*)d_out;

    int N = in_sizes[0] / HID;
    int E = in_sizes[1] / 2;
    int L = in_sizes[5] / (HID * HID);
    int G = out_size / HID;
    int EMB = (L + 1) * HID;

    const int* src = edge_index;
    const int* dst = edge_index + E;

    char* w = (char*)d_ws;
    auto alloc = [&](size_t bytes) -> char* {
        char* p = w;
        w += (bytes + 255) & ~(size_t)255;
        return p;
    };
    float* h      = (float*)alloc((size_t)N * HID * 4);
    float* z      = (float*)alloc((size_t)N * HID * 4);
    float* tmp    = (float*)alloc((size_t)N * HID * 4);
    float* xres   = (float*)alloc((size_t)N * HID * 4);
    float* pooled = (float*)alloc((size_t)G * EMB * 4);
    int* deg      = (int*)alloc((size_t)(N + 1) * 4);
    int* row_ptr  = (int*)alloc((size_t)(N + 1) * 4);
    int* pos      = (int*)alloc((size_t)(N + 1) * 4);
    int* csr_src  = (int*)alloc((size_t)E * 4);
    int* gstart   = (int*)alloc((size_t)(G + 1) * 4);
    (void)ws_size; (void)n_in;

    int eb = (E + 255) / 256;

    // CSR by dst (rebuilt every call; inputs constant -> same result)
    zero_i32<<<(N + 255) / 256, 256, 0, stream>>>(deg, N);
    count_deg<<<eb, 256, 0, stream>>>(dst, deg, E);
    scan_deg<<<1, 1024, 0, stream>>>(deg, row_ptr, pos, N);
    fill_csr<<<eb, 256, 0, stream>>>(src, dst, pos, csr_src, E);
    graph_starts<<<1, 256, 0, stream>>>(batch, gstart, N, G);

    int gb = (N + 15) / 16;

    // pre linear: h = x@pre_w + pre_b ; xres = h ; pooled slice 0
    linear128<false, false, true><<<gb, 256, 0, stream>>>(x, pre_w, pre_b, nullptr, h, xres, N);
    pool_kernel<<<G, HID, 0, stream>>>(h, gstart, pooled, 0, EMB);

    for (int i = 0; i < L; i++) {
        agg_kernel<<<(N + 1) / 2, 256, 0, stream>>>(h, row_ptr, csr_src, z, N);
        linear128<true, false, false><<<gb, 256, 0, stream>>>(
            z, conv_w1 + (size_t)i * HID * HID, conv_b1 + i * HID, nullptr, tmp, nullptr, N);
        if (i & 1) {
            // z2 = tmp@W2+b2 + xres ; xres = z2 ; h = relu(z2)
            linear128<true, true, true><<<gb, 256, 0, stream>>>(
                tmp, conv_w2 + (size_t)i * HID * HID, conv_b2 + i * HID, xres, h, xres, N);
        } else {
            linear128<true, false, false><<<gb, 256, 0, stream>>>(
                tmp, conv_w2 + (size_t)i * HID * HID, conv_b2 + i * HID, nullptr, h, nullptr, N);
        }
        pool_kernel<<<G, HID, 0, stream>>>(h, gstart, pooled, (i + 1) * HID, EMB);
    }

    post_kernel<<<G, HID, (EMB + HID) * sizeof(float), stream>>>(
        pooled, post_w1, post_b1, post_w2, post_b2, outp, EMB);
}

// Round 2
// 1784.099 us; speedup vs baseline: 1.6152x; 1.6152x over previous
//
#include <hip/hip_runtime.h>
#include <hip/hip_bf16.h>

#define HID 128

// ---------------- utility kernels ----------------

__global__ void zero_i32(int* __restrict__ p, int n) {
    int i = blockIdx.x * blockDim.x + threadIdx.x;
    if (i < n) p[i] = 0;
}

__global__ void count_deg(const int* __restrict__ dst, int* __restrict__ deg, int E) {
    int e = blockIdx.x * blockDim.x + threadIdx.x;
    if (e < E) atomicAdd(&deg[dst[e]], 1);
}

// single-block exclusive scan over deg[0..n) -> row_ptr[0..n], pos copy
__global__ __launch_bounds__(1024) void scan_deg(const int* __restrict__ deg,
                                                 int* __restrict__ row_ptr,
                                                 int* __restrict__ pos, int n) {
    __shared__ int sums[1024];
    int t = threadIdx.x;
    int chunk = (n + 1023) / 1024;
    int lo = t * chunk, hi = min(lo + chunk, n);
    int s = 0;
    for (int i = lo; i < hi; i++) s += deg[i];
    sums[t] = s;
    __syncthreads();
    for (int off = 1; off < 1024; off <<= 1) {
        int v = (t >= off) ? sums[t - off] : 0;
        __syncthreads();
        sums[t] += v;
        __syncthreads();
    }
    int excl = (t == 0) ? 0 : sums[t - 1];
    for (int i = lo; i < hi; i++) { row_ptr[i] = excl; pos[i] = excl; excl += deg[i]; }
    if (t == 0) row_ptr[n] = sums[1023];
}

__global__ void fill_csr(const int* __restrict__ src, const int* __restrict__ dst,
                         int* __restrict__ pos, int* __restrict__ csr_src, int E) {
    int e = blockIdx.x * blockDim.x + threadIdx.x;
    if (e < E) {
        int p = atomicAdd(&pos[dst[e]], 1);
        csr_src[p] = src[e];
    }
}

// gstart[g] = lower_bound(batch, g), g in [0, G]; batch is sorted
__global__ void graph_starts(const int* __restrict__ batch, int* __restrict__ gstart,
                             int n, int G) {
    int g = blockIdx.x * blockDim.x + threadIdx.x;
    if (g > G) return;
    int lo = 0, hi = n;
    while (lo < hi) { int m = (lo + hi) >> 1; if (batch[m] < g) lo = m + 1; else hi = m; }
    gstart[g] = lo;
}

// z[n] = h[n] + sum_{e in in-edges(n)} h[src(e)]
// 32 lanes per node (float4 per lane), 8 nodes per 256-thread block
__global__ __launch_bounds__(256) void agg_kernel(const float* __restrict__ h,
                                                  const int* __restrict__ row_ptr,
                                                  const int* __restrict__ csr_src,
                                                  float* __restrict__ z, int N) {
    int node = blockIdx.x * 8 + (threadIdx.x >> 5);
    int lane = threadIdx.x & 31;
    if (node >= N) return;
    const float4* h4 = (const float4*)h;
    float4 s = h4[(size_t)node * 32 + lane];
    int e0 = row_ptr[node], e1 = row_ptr[node + 1];
    for (int e = e0; e < e1; e++) {
        int srcn = csr_src[e];
        float4 v = h4[(size_t)srcn * 32 + lane];
        s.x += v.x; s.y += v.y; s.z += v.z; s.w += v.w;
    }
    ((float4*)z)[(size_t)node * 32 + lane] = s;
}

// out[r][c] = act( sum_k in[r][k]*W[k][c] + bias[c] [+ res[r][c]] )
// optional pre-activation copy to pre_out (used for xres update)
template <bool RELU, bool ADD_RES, bool WRITE_PRE>
__global__ __launch_bounds__(256) void linear128(const float* __restrict__ in,
                                                 const float* __restrict__ W,
                                                 const float* __restrict__ bias,
                                                 const float* __restrict__ res,
                                                 float* __restrict__ out,
                                                 float* __restrict__ pre_out, int M) {
    __shared__ float Wl[HID * HID];
    __shared__ float zl[8][HID];
    int t = threadIdx.x;
    {
        const float4* W4 = (const float4*)W;
        float4* Wl4 = (float4*)Wl;
        for (int i = t; i < HID * HID / 4; i += 256) Wl4[i] = W4[i];
    }
    int c = t & 127, half = t >> 7;
    float bc = bias[c];
    int row0 = blockIdx.x * 16;
    for (int sgo = 0; sgo < 16; sgo += 8) {
        int rbase = row0 + sgo;
        __syncthreads();   // protects Wl on first iter, zl reuse after
        {
            int srow = t >> 5;
            int scol = (t & 31) * 4;
            if (rbase + srow < M)
                *(float4*)&zl[srow][scol] =
                    *(const float4*)&in[(size_t)(rbase + srow) * HID + scol];
        }
        __syncthreads();
        int r0 = half * 4;
        float acc0 = 0.f, acc1 = 0.f, acc2 = 0.f, acc3 = 0.f;
#pragma unroll 8
        for (int k4 = 0; k4 < HID / 4; k4++) {
            float4 a0 = *(const float4*)&zl[r0 + 0][k4 * 4];
            float4 a1 = *(const float4*)&zl[r0 + 1][k4 * 4];
            float4 a2 = *(const float4*)&zl[r0 + 2][k4 * 4];
            float4 a3 = *(const float4*)&zl[r0 + 3][k4 * 4];
            float w0 = Wl[(k4 * 4 + 0) * HID + c];
            float w1 = Wl[(k4 * 4 + 1) * HID + c];
            float w2 = Wl[(k4 * 4 + 2) * HID + c];
            float w3 = Wl[(k4 * 4 + 3) * HID + c];
            acc0 += a0.x * w0 + a0.y * w1 + a0.z * w2 + a0.w * w3;
            acc1 += a1.x * w0 + a1.y * w1 + a1.z * w2 + a1.w * w3;
            acc2 += a2.x * w0 + a2.y * w1 + a2.z * w2 + a2.w * w3;
            acc3 += a3.x * w0 + a3.y * w1 + a3.z * w2 + a3.w * w3;
        }
        float accs[4] = {acc0, acc1, acc2, acc3};
#pragma unroll
        for (int j = 0; j < 4; j++) {
            int r = rbase + r0 + j;
            if (r < M) {
                float v = accs[j] + bc;
                if (ADD_RES) v += res[(size_t)r * HID + c];
                if (WRITE_PRE) pre_out[(size_t)r * HID + c] = v;
                out[(size_t)r * HID + c] = RELU ? fmaxf(v, 0.f) : v;
            }
        }
    }
}

// pooled[g][off + c] = sum over nodes of graph g of h[n][c]   (deterministic)
// 16 waves/block: 8 row-groups x 128 cols, LDS tree reduce
__global__ __launch_bounds__(1024) void pool_kernel(const float* __restrict__ h,
                                                    const int* __restrict__ gstart,
                                                    float* __restrict__ pooled,
                                                    int off, int EMB) {
    int g = blockIdx.x;
    int c = threadIdx.x & 127;
    int rg = threadIdx.x >> 7;   // 0..7
    __shared__ float part[8][HID];
    int n0 = gstart[g], n1 = gstart[g + 1];
    float s = 0.f;
    for (int n = n0 + rg; n < n1; n += 8) s += h[(size_t)n * HID + c];
    part[rg][c] = s;
    __syncthreads();
    if (rg == 0) {
        float tsum = 0.f;
#pragma unroll
        for (int r = 0; r < 8; r++) tsum += part[r][c];
        pooled[(size_t)g * EMB + off + c] = tsum;
    }
}

// out[g] = relu(pooled[g] @ w1 + b1) @ w2 + b2
__global__ __launch_bounds__(128) void post_kernel(const float* __restrict__ pooled,
                                                   const float* __restrict__ w1,
                                                   const float* __restrict__ b1,
                                                   const float* __restrict__ w2,
                                                   const float* __restrict__ b2,
                                                   float* __restrict__ out, int EMB) {
    int g = blockIdx.x, c = threadIdx.x;
    extern __shared__ float smem[];           // EMB + HID floats
    float* prow = smem;
    float* y1 = smem + EMB;
    for (int k = c; k < EMB; k += 128) prow[k] = pooled[(size_t)g * EMB + k];
    __syncthreads();
    float acc = b1[c];
    for (int k = 0; k < EMB; k++) acc += prow[k] * w1[k * HID + c];
    y1[c] = fmaxf(acc, 0.f);
    __syncthreads();
    float acc2 = b2[c];
    for (int k = 0; k < HID; k++) acc2 += y1[k] * w2[k * HID + c];
    out[(size_t)g * HID + c] = acc2;
}

// ---------------- launch ----------------

extern "C" void kernel_launch(void* const* d_in, const int* in_sizes, int n_in,
                              void* d_out, int out_size, void* d_ws, size_t ws_size,
                              hipStream_t stream) {
    const float* x       = (const float*)d_in[0];
    const int* edge_index= (const int*)d_in[1];
    const int* batch     = (const int*)d_in[2];
    const float* pre_w   = (const float*)d_in[3];
    const float* pre_b   = (const float*)d_in[4];
    const float* conv_w1 = (const float*)d_in[5];
    const float* conv_b1 = (const float*)d_in[6];
    const float* conv_w2 = (const float*)d_in[7];
    const float* conv_b2 = (const float*)d_in[8];
    const float* post_w1 = (const float*)d_in[9];
    const float* post_b1 = (const float*)d_in[10];
    const float* post_w2 = (const float*)d_in[11];
    const float* post_b2 = (const float*)d_in[12];
    float* outp = (float*)d_out;

    int N = in_sizes[0] / HID;
    int E = in_sizes[1] / 2;
    int L = in_sizes[5] / (HID * HID);
    int G = out_size / HID;
    int EMB = (L + 1) * HID;

    const int* src = edge_index;
    const int* dst = edge_index + E;

    char* w = (char*)d_ws;
    auto alloc = [&](size_t bytes) -> char* {
        char* p = w;
        w += (bytes + 255) & ~(size_t)255;
        return p;
    };
    float* h      = (float*)alloc((size_t)N * HID * 4);
    float* z      = (float*)alloc((size_t)N * HID * 4);
    float* tmp    = (float*)alloc((size_t)N * HID * 4);
    float* xres   = (float*)alloc((size_t)N * HID * 4);
    float* pooled = (float*)alloc((size_t)G * EMB * 4);
    int* deg      = (int*)alloc((size_t)(N + 1) * 4);
    int* row_ptr  = (int*)alloc((size_t)(N + 1) * 4);
    int* pos      = (int*)alloc((size_t)(N + 1) * 4);
    int* csr_src  = (int*)alloc((size_t)E * 4);
    int* gstart   = (int*)alloc((size_t)(G + 1) * 4);
    (void)ws_size; (void)n_in;

    int eb = (E + 255) / 256;

    // CSR by dst (rebuilt every call; inputs constant -> same result)
    zero_i32<<<(N + 255) / 256, 256, 0, stream>>>(deg, N);
    count_deg<<<eb, 256, 0, stream>>>(dst, deg, E);
    scan_deg<<<1, 1024, 0, stream>>>(deg, row_ptr, pos, N);
    fill_csr<<<eb, 256, 0, stream>>>(src, dst, pos, csr_src, E);
    graph_starts<<<1, 256, 0, stream>>>(batch, gstart, N, G);

    int gb = (N + 15) / 16;

    // pre linear: h = x@pre_w + pre_b ; xres = h ; pooled slice 0
    linear128<false, false, true><<<gb, 256, 0, stream>>>(x, pre_w, pre_b, nullptr, h, xres, N);
    pool_kernel<<<G, 1024, 0, stream>>>(h, gstart, pooled, 0, EMB);

    for (int i = 0; i < L; i++) {
        agg_kernel<<<(N + 7) / 8, 256, 0, stream>>>(h, row_ptr, csr_src, z, N);
        linear128<true, false, false><<<gb, 256, 0, stream>>>(
            z, conv_w1 + (size_t)i * HID * HID, conv_b1 + i * HID, nullptr, tmp, nullptr, N);
        if (i & 1) {
            // z2 = tmp@W2+b2 + xres ; xres = z2 ; h = relu(z2)
            linear128<true, true, true><<<gb, 256, 0, stream>>>(
                tmp, conv_w2 + (size_t)i * HID * HID, conv_b2 + i * HID, xres, h, xres, N);
        } else {
            linear128<true, false, false><<<gb, 256, 0, stream>>>(
                tmp, conv_w2 + (size_t)i * HID * HID, conv_b2 + i * HID, nullptr, h, nullptr, N);
        }
        pool_kernel<<<G, 1024, 0, stream>>>(h, gstart, pooled, (i + 1) * HID, EMB);
    }

    post_kernel<<<G, HID, (EMB + HID) * sizeof(float), stream>>>(
        pooled, post_w1, post_b1, post_w2, post_b2, outp, EMB);
}

// Round 3
// 791.659 us; speedup vs baseline: 3.6399x; 2.2536x over previous
//
#include <hip/hip_runtime.h>
#include <hip/hip_bf16.h>

#define HID 128

using bf16x8 = __attribute__((ext_vector_type(8))) short;
using f32x4  = __attribute__((ext_vector_type(4))) float;

__device__ inline float bf2f(unsigned int u16) {   // u16: low 16 bits hold bf16
    union { float f; unsigned int i; } v; v.i = u16 << 16; return v.f;
}
__device__ inline unsigned short f2bf(float f) {
    __hip_bfloat16 h = __float2bfloat16(f);        // RNE
    return *reinterpret_cast<unsigned short*>(&h);
}

// ---------------- CSR build ----------------

__global__ void zero_i32(int* __restrict__ p, int n) {
    int i = blockIdx.x * blockDim.x + threadIdx.x;
    if (i < n) p[i] = 0;
}

__global__ void count_deg(const int* __restrict__ dst, int* __restrict__ deg, int E) {
    int e = blockIdx.x * blockDim.x + threadIdx.x;
    if (e < E) atomicAdd(&deg[dst[e]], 1);
}

// per-256-block sums of deg
__global__ __launch_bounds__(256) void block_sums(const int* __restrict__ deg,
                                                  int* __restrict__ bsum, int n) {
    __shared__ int red[256];
    int t = threadIdx.x;
    int i = blockIdx.x * 256 + t;
    red[t] = (i < n) ? deg[i] : 0;
    __syncthreads();
    for (int off = 128; off > 0; off >>= 1) {
        if (t < off) red[t] += red[t + off];
        __syncthreads();
    }
    if (t == 0) bsum[blockIdx.x] = red[0];
}

// exclusive scan of block sums (nb <= 1024), single block
__global__ __launch_bounds__(1024) void scan_bsums(const int* __restrict__ bsum,
                                                   int* __restrict__ bstart, int nb) {
    __shared__ int s[1024];
    int t = threadIdx.x;
    s[t] = (t < nb) ? bsum[t] : 0;
    __syncthreads();
    for (int off = 1; off < 1024; off <<= 1) {
        int v = (t >= off) ? s[t - off] : 0;
        __syncthreads();
        s[t] += v;
        __syncthreads();
    }
    if (t < nb) bstart[t] = (t == 0) ? 0 : s[t - 1];
}

// within-block exclusive scan + add block start -> row_ptr, pos
__global__ __launch_bounds__(256) void scan_within(const int* __restrict__ deg,
                                                   const int* __restrict__ bstart,
                                                   int* __restrict__ row_ptr,
                                                   int* __restrict__ pos, int n) {
    __shared__ int s[256];
    int b = blockIdx.x, t = threadIdx.x;
    int i = b * 256 + t;
    int v = (i < n) ? deg[i] : 0;
    s[t] = v;
    __syncthreads();
    for (int off = 1; off < 256; off <<= 1) {
        int u = (t >= off) ? s[t - off] : 0;
        __syncthreads();
        s[t] += u;
        __syncthreads();
    }
    if (i < n) {
        int excl = bstart[b] + s[t] - v;
        row_ptr[i] = excl;
        pos[i] = excl;
        if (i == n - 1) row_ptr[n] = bstart[b] + s[t];
    }
}

__global__ void fill_csr(const int* __restrict__ src, const int* __restrict__ dst,
                         int* __restrict__ pos, int* __restrict__ csr_src, int E) {
    int e = blockIdx.x * blockDim.x + threadIdx.x;
    if (e < E) {
        int p = atomicAdd(&pos[dst[e]], 1);
        csr_src[p] = src[e];
    }
}

__global__ void graph_starts(const int* __restrict__ batch, int* __restrict__ gstart,
                             int n, int G) {
    int g = blockIdx.x * blockDim.x + threadIdx.x;
    if (g > G) return;
    int lo = 0, hi = n;
    while (lo < hi) { int m = (lo + hi) >> 1; if (batch[m] < g) lo = m + 1; else hi = m; }
    gstart[g] = lo;
}

// ---------------- conversions ----------------

// fp32 -> bf16, 8 elements per thread
__global__ void f32_to_bf16_vec(const float* __restrict__ in,
                                unsigned short* __restrict__ out, int n8) {
    int i = blockIdx.x * blockDim.x + threadIdx.x;
    if (i >= n8) return;
    const float4* in4 = (const float4*)in;
    float4 a = in4[i * 2], b = in4[i * 2 + 1];
    uint4 o;
    o.x = f2bf(a.x) | ((unsigned)f2bf(a.y) << 16);
    o.y = f2bf(a.z) | ((unsigned)f2bf(a.w) << 16);
    o.z = f2bf(b.x) | ((unsigned)f2bf(b.y) << 16);
    o.w = f2bf(b.z) | ((unsigned)f2bf(b.w) << 16);
    ((uint4*)out)[i] = o;
}

// W[mat][k][c] fp32 -> Wt[mat][c][k] bf16 (writes coalesced)
__global__ void transpose_w(const float* __restrict__ W,
                            unsigned short* __restrict__ Wt, int total) {
    int tid = blockIdx.x * blockDim.x + threadIdx.x;
    if (tid >= total) return;
    int mat = tid >> 14;
    int idx = tid & 16383;
    int c = idx >> 7, k = idx & 127;
    Wt[tid] = f2bf(W[((size_t)mat << 14) + k * HID + c]);
}

// ---------------- aggregation: z = h + sum_in-edges h[src], bf16 ----------------

__global__ __launch_bounds__(256) void agg_kernel(const unsigned short* __restrict__ h,
                                                  const int* __restrict__ row_ptr,
                                                  const int* __restrict__ csr_src,
                                                  unsigned short* __restrict__ z, int N) {
    int node = blockIdx.x * 16 + (threadIdx.x >> 4);
    int lane = threadIdx.x & 15;
    if (node >= N) return;
    const uint4* h4 = (const uint4*)h;
    uint4 u = h4[(size_t)node * 16 + lane];
    float s0 = bf2f(u.x & 0xffff), s1 = bf2f(u.x >> 16);
    float s2 = bf2f(u.y & 0xffff), s3 = bf2f(u.y >> 16);
    float s4 = bf2f(u.z & 0xffff), s5 = bf2f(u.z >> 16);
    float s6 = bf2f(u.w & 0xffff), s7 = bf2f(u.w >> 16);
    int e0 = row_ptr[node], e1 = row_ptr[node + 1];
    for (int e = e0; e < e1; e++) {
        uint4 v = h4[(size_t)csr_src[e] * 16 + lane];
        s0 += bf2f(v.x & 0xffff); s1 += bf2f(v.x >> 16);
        s2 += bf2f(v.y & 0xffff); s3 += bf2f(v.y >> 16);
        s4 += bf2f(v.z & 0xffff); s5 += bf2f(v.z >> 16);
        s6 += bf2f(v.w & 0xffff); s7 += bf2f(v.w >> 16);
    }
    uint4 o;
    o.x = f2bf(s0) | ((unsigned)f2bf(s1) << 16);
    o.y = f2bf(s2) | ((unsigned)f2bf(s3) << 16);
    o.z = f2bf(s4) | ((unsigned)f2bf(s5) << 16);
    o.w = f2bf(s6) | ((unsigned)f2bf(s7) << 16);
    ((uint4*)z)[(size_t)node * 16 + lane] = o;
}

// ---------------- MFMA linear: out[r][c] = act(in[r][:]·W[:][c] + b [+res]) ----------------
// in bf16 [M][128]; Wt bf16 [128 cols][128 k] (pre-transposed); out bf16;
// res/pre_out fp32. Block 256 thr = 4 waves; wave = 32 rows x 128 cols.
// A frag: lane row=l&15, k=(l>>4)*8+j (contig). B frag: lane col=l&15, same k.
// C/D: col=lane&15, row=(lane>>4)*4+reg  [m89 layout].
template <bool RELU, bool ADD_RES, bool WRITE_PRE>
__global__ __launch_bounds__(256) void linear_mfma(const unsigned short* __restrict__ in,
                                                   const unsigned short* __restrict__ Wt,
                                                   const float* __restrict__ bias,
                                                   const float* __restrict__ res,
                                                   unsigned short* __restrict__ out,
                                                   float* __restrict__ pre_out, int M) {
    int tid = threadIdx.x;
    int wave = tid >> 6, lane = tid & 63;
    int l15 = lane & 15, l4 = lane >> 4;
    int rowbase = blockIdx.x * 128 + wave * 32;
    f32x4 acc[2][8];
#pragma unroll
    for (int rt = 0; rt < 2; rt++)
#pragma unroll
        for (int ct = 0; ct < 8; ct++) acc[rt][ct] = (f32x4){0.f, 0.f, 0.f, 0.f};

    int r0 = min(rowbase + l15, M - 1);
    int r1 = min(rowbase + 16 + l15, M - 1);
#pragma unroll
    for (int kk = 0; kk < 4; kk++) {
        int k0 = kk * 32 + l4 * 8;
        bf16x8 a0 = *(const bf16x8*)&in[(size_t)r0 * HID + k0];
        bf16x8 a1 = *(const bf16x8*)&in[(size_t)r1 * HID + k0];
        bf16x8 b[8];
#pragma unroll
        for (int ct = 0; ct < 8; ct++)
            b[ct] = *(const bf16x8*)&Wt[(size_t)(ct * 16 + l15) * HID + k0];
#pragma unroll
        for (int ct = 0; ct < 8; ct++) {
            acc[0][ct] = __builtin_amdgcn_mfma_f32_16x16x32_bf16(a0, b[ct], acc[0][ct], 0, 0, 0);
            acc[1][ct] = __builtin_amdgcn_mfma_f32_16x16x32_bf16(a1, b[ct], acc[1][ct], 0, 0, 0);
        }
    }
#pragma unroll
    for (int ct = 0; ct < 8; ct++) {
        int col = ct * 16 + l15;
        float bc = bias[col];
#pragma unroll
        for (int rt = 0; rt < 2; rt++) {
#pragma unroll
            for (int j = 0; j < 4; j++) {
                int r = rowbase + rt * 16 + l4 * 4 + j;
                if (r < M) {
                    float v = acc[rt][ct][j] + bc;
                    if (ADD_RES) v += res[(size_t)r * HID + col];
                    if (WRITE_PRE) pre_out[(size_t)r * HID + col] = v;
                    out[(size_t)r * HID + col] = f2bf(RELU ? fmaxf(v, 0.f) : v);
                }
            }
        }
    }
}

// ---------------- pooling (bf16 in, fp32 out) ----------------

__global__ __launch_bounds__(1024) void pool_kernel(const unsigned short* __restrict__ h,
                                                    const int* __restrict__ gstart,
                                                    float* __restrict__ pooled,
                                                    int off, int EMB) {
    int g = blockIdx.x;
    int c = threadIdx.x & 127;
    int rg = threadIdx.x >> 7;  // 0..7
    __shared__ float part[8][HID];
    int n0 = gstart[g], n1 = gstart[g + 1];
    float s = 0.f;
    for (int n = n0 + rg; n < n1; n += 8) s += bf2f(h[(size_t)n * HID + c]);
    part[rg][c] = s;
    __syncthreads();
    if (rg == 0) {
        float tsum = 0.f;
#pragma unroll
        for (int r = 0; r < 8; r++) tsum += part[r][c];
        pooled[(size_t)g * EMB + off + c] = tsum;
    }
}

// ---------------- post MLP (fp32) ----------------

__global__ __launch_bounds__(128) void post_kernel(const float* __restrict__ pooled,
                                                   const float* __restrict__ w1,
                                                   const float* __restrict__ b1,
                                                   const float* __restrict__ w2,
                                                   const float* __restrict__ b2,
                                                   float* __restrict__ out, int EMB) {
    int g = blockIdx.x, c = threadIdx.x;
    extern __shared__ float smem[];  // EMB + HID floats
    float* prow = smem;
    float* y1 = smem + EMB;
    for (int k = c; k < EMB; k += 128) prow[k] = pooled[(size_t)g * EMB + k];
    __syncthreads();
    float acc = b1[c];
    for (int k = 0; k < EMB; k++) acc += prow[k] * w1[k * HID + c];
    y1[c] = fmaxf(acc, 0.f);
    __syncthreads();
    float acc2 = b2[c];
    for (int k = 0; k < HID; k++) acc2 += y1[k] * w2[k * HID + c];
    out[(size_t)g * HID + c] = acc2;
}

// ---------------- launch ----------------

extern "C" void kernel_launch(void* const* d_in, const int* in_sizes, int n_in,
                              void* d_out, int out_size, void* d_ws, size_t ws_size,
                              hipStream_t stream) {
    const float* x       = (const float*)d_in[0];
    const int* edge_index= (const int*)d_in[1];
    const int* batch     = (const int*)d_in[2];
    const float* pre_w   = (const float*)d_in[3];
    const float* pre_b   = (const float*)d_in[4];
    const float* conv_w1 = (const float*)d_in[5];
    const float* conv_b1 = (const float*)d_in[6];
    const float* conv_w2 = (const float*)d_in[7];
    const float* conv_b2 = (const float*)d_in[8];
    const float* post_w1 = (const float*)d_in[9];
    const float* post_b1 = (const float*)d_in[10];
    const float* post_w2 = (const float*)d_in[11];
    const float* post_b2 = (const float*)d_in[12];
    float* outp = (float*)d_out;

    int N = in_sizes[0] / HID;
    int E = in_sizes[1] / 2;
    int L = in_sizes[5] / (HID * HID);
    int G = out_size / HID;
    int EMB = (L + 1) * HID;

    const int* src = edge_index;
    const int* dst = edge_index + E;

    char* w = (char*)d_ws;
    auto alloc = [&](size_t bytes) -> char* {
        char* p = w;
        w += (bytes + 255) & ~(size_t)255;
        return p;
    };
    unsigned short* x_bf  = (unsigned short*)alloc((size_t)N * HID * 2);
    unsigned short* h_bf  = (unsigned short*)alloc((size_t)N * HID * 2);
    unsigned short* z_bf  = (unsigned short*)alloc((size_t)N * HID * 2);
    unsigned short* t_bf  = (unsigned short*)alloc((size_t)N * HID * 2);
    float* xres   = (float*)alloc((size_t)N * HID * 4);
    float* pooled = (float*)alloc((size_t)G * EMB * 4);
    unsigned short* Wt_pre = (unsigned short*)alloc((size_t)HID * HID * 2);
    unsigned short* Wt_c1  = (unsigned short*)alloc((size_t)L * HID * HID * 2);
    unsigned short* Wt_c2  = (unsigned short*)alloc((size_t)L * HID * HID * 2);
    int* deg      = (int*)alloc((size_t)(N + 1) * 4);
    int* row_ptr  = (int*)alloc((size_t)(N + 1) * 4);
    int* pos      = (int*)alloc((size_t)(N + 1) * 4);
    int* bsum     = (int*)alloc((size_t)1024 * 4);
    int* bstart   = (int*)alloc((size_t)1024 * 4);
    int* csr_src  = (int*)alloc((size_t)E * 4);
    int* gstart   = (int*)alloc((size_t)(G + 1) * 4);
    (void)ws_size; (void)n_in;

    int eb = (E + 255) / 256;
    int nb = (N + 255) / 256;

    // CSR by dst (rebuilt every call; deterministic inputs)
    zero_i32<<<nb, 256, 0, stream>>>(deg, N);
    count_deg<<<eb, 256, 0, stream>>>(dst, deg, E);
    block_sums<<<nb, 256, 0, stream>>>(deg, bsum, N);
    scan_bsums<<<1, 1024, 0, stream>>>(bsum, bstart, nb);
    scan_within<<<nb, 256, 0, stream>>>(deg, bstart, row_ptr, pos, N);
    fill_csr<<<eb, 256, 0, stream>>>(src, dst, pos, csr_src, E);
    graph_starts<<<1, 256, 0, stream>>>(batch, gstart, N, G);

    // conversions
    f32_to_bf16_vec<<<(N * HID / 8 + 255) / 256, 256, 0, stream>>>(x, x_bf, N * HID / 8);
    transpose_w<<<(HID * HID + 255) / 256, 256, 0, stream>>>(pre_w, Wt_pre, HID * HID);
    transpose_w<<<(L * HID * HID + 255) / 256, 256, 0, stream>>>(conv_w1, Wt_c1, L * HID * HID);
    transpose_w<<<(L * HID * HID + 255) / 256, 256, 0, stream>>>(conv_w2, Wt_c2, L * HID * HID);

    int gb = (N + 127) / 128;

    // pre linear: h = x@pre_w + pre_b ; xres = h (fp32)
    linear_mfma<false, false, true><<<gb, 256, 0, stream>>>(x_bf, Wt_pre, pre_b, nullptr, h_bf, xres, N);
    pool_kernel<<<G, 1024, 0, stream>>>(h_bf, gstart, pooled, 0, EMB);

    for (int i = 0; i < L; i++) {
        agg_kernel<<<(N + 15) / 16, 256, 0, stream>>>(h_bf, row_ptr, csr_src, z_bf, N);
        linear_mfma<true, false, false><<<gb, 256, 0, stream>>>(
            z_bf, Wt_c1 + (size_t)i * HID * HID, conv_b1 + i * HID, nullptr, t_bf, nullptr, N);
        if (i & 1) {
            // z2 = t@W2+b2 + xres ; xres = z2 ; h = relu(z2)
            linear_mfma<true, true, true><<<gb, 256, 0, stream>>>(
                t_bf, Wt_c2 + (size_t)i * HID * HID, conv_b2 + i * HID, xres, h_bf, xres, N);
        } else {
            linear_mfma<true, false, false><<<gb, 256, 0, stream>>>(
                t_bf, Wt_c2 + (size_t)i * HID * HID, conv_b2 + i * HID, nullptr, h_bf, nullptr, N);
        }
        pool_kernel<<<G, 1024, 0, stream>>>(h_bf, gstart, pooled, (i + 1) * HID, EMB);
    }

    post_kernel<<<G, HID, (EMB + HID) * sizeof(float), stream>>>(
        pooled, post_w1, post_b1, post_w2, post_b2, outp, EMB);
}